// Round 1
// baseline (134.604 us; speedup 1.0000x reference)
//
#include <hip/hip_runtime.h>
#include <cstdint>
#include <cstddef>

// ---------------------------------------------------------------------------
// CQAttention: S = (C*w4mlu)Q^T + Cw4C + (Qw4Q)^T + bias  (clipped to +-15)
// S1 = masked_softmax(S, Qmask, axis=lq); S2 = masked_softmax(S, Cmask, axis=lc)
// A = S1 Q ; Bt = S1 (S2^T C)   [reassociated]
// out = [C, A, C*A, C*Bt]  (B=16, Lc=1024, Lq=256, d=512)
// GEMMs in bf16 MFMA (fp32 accum); softmax in fp32.
// ---------------------------------------------------------------------------

typedef __attribute__((ext_vector_type(8))) short short8;
typedef __attribute__((ext_vector_type(4))) short short4v;
typedef __attribute__((ext_vector_type(4))) float f32x4;
typedef __attribute__((ext_vector_type(8))) __bf16 bf16x8;

__device__ __forceinline__ short f2bf(float f) {
  unsigned u = __builtin_bit_cast(unsigned, f);
  u += 0x7fffu + ((u >> 16) & 1u);   // RNE
  return (short)(u >> 16);
}

__device__ __forceinline__ float wave_sum(float v) {
#pragma unroll
  for (int i = 32; i > 0; i >>= 1) v += __shfl_xor(v, i, 64);
  return v;
}
__device__ __forceinline__ float wave_max(float v) {
#pragma unroll
  for (int i = 32; i > 0; i >>= 1) v = fmaxf(v, __shfl_xor(v, i, 64));
  return v;
}

__device__ __forceinline__ void gload16(const void* g, void* l) {
  __builtin_amdgcn_global_load_lds(
      (const __attribute__((address_space(1))) void*)g,
      (__attribute__((address_space(3))) void*)l, 16, 0, 0);
}

__device__ __forceinline__ f32x4 mfma16(short8 a, short8 b, f32x4 c) {
  return __builtin_amdgcn_mfma_f32_16x16x32_bf16(
      __builtin_bit_cast(bf16x8, a), __builtin_bit_cast(bf16x8, b), c, 0, 0, 0);
}

// ---------------- prep kernels: row dots + bf16 casts ----------------------

// one wave per C row: sub0[row] = C_row . w4C ; CW = bf16(C * w4mlu)
__global__ __launch_bounds__(256) void prep_c(const float* __restrict__ C,
                                              const float* __restrict__ w4C,
                                              const float* __restrict__ w4mlu,
                                              float* __restrict__ sub0,
                                              short* __restrict__ CW) {
  int wave = threadIdx.x >> 6, lane = threadIdx.x & 63;
  int row = blockIdx.x * 4 + wave;
  const float* c = C + (size_t)row * 512 + lane * 8;
  const float* wv = w4C + lane * 8;
  const float* wm = w4mlu + lane * 8;
  float4 c0 = *(const float4*)c, c1 = *(const float4*)(c + 4);
  float4 v0 = *(const float4*)wv, v1 = *(const float4*)(wv + 4);
  float4 m0 = *(const float4*)wm, m1 = *(const float4*)(wm + 4);
  float dot = c0.x * v0.x + c0.y * v0.y + c0.z * v0.z + c0.w * v0.w +
              c1.x * v1.x + c1.y * v1.y + c1.z * v1.z + c1.w * v1.w;
  dot = wave_sum(dot);
  if (lane == 0) sub0[row] = dot;
  short8 s;
  s[0] = f2bf(c0.x * m0.x); s[1] = f2bf(c0.y * m0.y);
  s[2] = f2bf(c0.z * m0.z); s[3] = f2bf(c0.w * m0.w);
  s[4] = f2bf(c1.x * m1.x); s[5] = f2bf(c1.y * m1.y);
  s[6] = f2bf(c1.z * m1.z); s[7] = f2bf(c1.w * m1.w);
  *(short8*)(CW + (size_t)row * 512 + lane * 8) = s;
}

// one wave per Q row: sub1[row] = Q_row . w4Q ; Qb = bf16(Q)
__global__ __launch_bounds__(256) void prep_q(const float* __restrict__ Q,
                                              const float* __restrict__ w4Q,
                                              float* __restrict__ sub1,
                                              short* __restrict__ Qb) {
  int wave = threadIdx.x >> 6, lane = threadIdx.x & 63;
  int row = blockIdx.x * 4 + wave;
  const float* q = Q + (size_t)row * 512 + lane * 8;
  const float* wv = w4Q + lane * 8;
  float4 q0 = *(const float4*)q, q1 = *(const float4*)(q + 4);
  float4 v0 = *(const float4*)wv, v1 = *(const float4*)(wv + 4);
  float dot = q0.x * v0.x + q0.y * v0.y + q0.z * v0.z + q0.w * v0.w +
              q1.x * v1.x + q1.y * v1.y + q1.z * v1.z + q1.w * v1.w;
  dot = wave_sum(dot);
  if (lane == 0) sub1[row] = dot;
  short8 s;
  s[0] = f2bf(q0.x); s[1] = f2bf(q0.y); s[2] = f2bf(q0.z); s[3] = f2bf(q0.w);
  s[4] = f2bf(q1.x); s[5] = f2bf(q1.y); s[6] = f2bf(q1.z); s[7] = f2bf(q1.w);
  *(short8*)(Qb + (size_t)row * 512 + lane * 8) = s;
}

// ---------------- generic batched transpose [R,Ccols] -> [Ccols,R] ---------

template <typename Tin, typename Tout>
__global__ __launch_bounds__(256) void transpose_k(const Tin* __restrict__ in,
                                                   Tout* __restrict__ out,
                                                   int R, int Ccols) {
  __shared__ Tout tile[32][33];
  size_t boff = (size_t)blockIdx.z * R * Ccols;
  const Tin* ip = in + boff;
  Tout* op = out + boff;
  int c0 = blockIdx.x * 32, r0 = blockIdx.y * 32;
  int tx = threadIdx.x & 31, ty = threadIdx.x >> 5;  // ty: 0..7
#pragma unroll
  for (int i = 0; i < 32; i += 8) {
    Tin v = ip[(size_t)(r0 + ty + i) * Ccols + c0 + tx];
    if constexpr (sizeof(Tin) == 4 && sizeof(Tout) == 2)
      tile[ty + i][tx] = f2bf((float)v);
    else
      tile[ty + i][tx] = (Tout)v;
  }
  __syncthreads();
#pragma unroll
  for (int i = 0; i < 32; i += 8)
    op[(size_t)(c0 + ty + i) * R + r0 + tx] = tile[tx][ty + i];
}

// ---------------- bf16 NT GEMM core: 128x128 tile, BK=32, 4 waves ----------
// A: [M,K] row-major (K contiguous), B: [N,K] row-major. D = A * B^T.

__device__ __forceinline__ void gemm_core(const short* __restrict__ A,
                                          const short* __restrict__ B, int K,
                                          int lda, int ldb, int m0, int n0,
                                          short* ldsA, short* ldsB,
                                          f32x4 (&acc)[4][4]) {
  const int tid = threadIdx.x;
  const int lane = tid & 63;
  const int wave = tid >> 6;
  const int wr = (wave >> 1) * 64, wc = (wave & 1) * 64;
  const int fr = lane & 15;
  const int fk = (lane >> 4) * 8;
  const int srow = tid >> 2;
  const int skoff = (tid & 3) * 8;

  const short* Ag = A + (size_t)(m0 + srow) * lda + skoff;
  const short* Ag2 = A + (size_t)(m0 + 64 + srow) * lda + skoff;
  const short* Bg = B + (size_t)(n0 + srow) * ldb + skoff;
  const short* Bg2 = B + (size_t)(n0 + 64 + srow) * ldb + skoff;
  short* la = ldsA + tid * 8;
  short* la2 = ldsA + 64 * 32 + tid * 8;
  short* lb = ldsB + tid * 8;
  short* lb2 = ldsB + 64 * 32 + tid * 8;

  for (int k0 = 0; k0 < K; k0 += 32) {
    gload16(Ag + k0, la);
    gload16(Ag2 + k0, la2);
    gload16(Bg + k0, lb);
    gload16(Bg2 + k0, lb2);
    __syncthreads();
    short8 af[4], bf[4];
#pragma unroll
    for (int m = 0; m < 4; ++m)
      af[m] = *(const short8*)(ldsA + (wr + m * 16 + fr) * 32 + fk);
#pragma unroll
    for (int n = 0; n < 4; ++n)
      bf[n] = *(const short8*)(ldsB + (wc + n * 16 + fr) * 32 + fk);
#pragma unroll
    for (int m = 0; m < 4; ++m)
#pragma unroll
      for (int n = 0; n < 4; ++n) acc[m][n] = mfma16(af[m], bf[n], acc[m][n]);
    __syncthreads();
  }
}

#define GEMM_PROLOGUE()                                        \
  __shared__ __attribute__((aligned(16))) short ldsA[128 * 32];\
  __shared__ __attribute__((aligned(16))) short ldsB[128 * 32];\
  const int b = blockIdx.z;                                    \
  const int m0 = blockIdx.x * 128, n0 = blockIdx.y * 128;      \
  f32x4 acc[4][4];                                             \
  {                                                            \
    f32x4 z = {0.f, 0.f, 0.f, 0.f};                            \
    _Pragma("unroll") for (int m = 0; m < 4; ++m)              \
        _Pragma("unroll") for (int n = 0; n < 4; ++n) acc[m][n] = z; \
  }                                                            \
  const int lane = threadIdx.x & 63, wave = threadIdx.x >> 6;  \
  const int wr = (wave >> 1) * 64, wc = (wave & 1) * 64;       \
  const int cr = (lane >> 4) * 4, cc = lane & 15;

// S = CW * Qb^T + sub0 + sub1 + bias, clip to [-15,15]. M=1024,N=256,K=512
__global__ __launch_bounds__(256) void gemm_S(const short* __restrict__ CW,
                                              const short* __restrict__ Qb,
                                              const float* __restrict__ sub0,
                                              const float* __restrict__ sub1,
                                              const float* __restrict__ bias,
                                              float* __restrict__ S) {
  GEMM_PROLOGUE();
  gemm_core(CW + (size_t)b * 1024 * 512, Qb + (size_t)b * 256 * 512, 512, 512,
            512, m0, n0, ldsA, ldsB, acc);
  float bv = bias[0];
  const float* s0 = sub0 + b * 1024;
  const float* s1 = sub1 + b * 256;
  float* Sb = S + (size_t)b * 1024 * 256;
#pragma unroll
  for (int m = 0; m < 4; ++m)
#pragma unroll
    for (int n = 0; n < 4; ++n)
#pragma unroll
      for (int i = 0; i < 4; ++i) {
        int r = m0 + wr + m * 16 + cr + i;
        int c = n0 + wc + n * 16 + cc;
        float v = acc[m][n][i] + s0[r] + s1[c] + bv;
        v = fminf(15.f, fmaxf(-15.f, v));
        Sb[(size_t)r * 256 + c] = v;
      }
}

// T = S2t * Ctb^T (bf16 out). M=256(lq), N=512(d), K=1024(lc)
__global__ __launch_bounds__(256) void gemm_T(const short* __restrict__ S2t,
                                              const short* __restrict__ Ctb,
                                              short* __restrict__ Tb) {
  GEMM_PROLOGUE();
  gemm_core(S2t + (size_t)b * 256 * 1024, Ctb + (size_t)b * 512 * 1024, 1024,
            1024, 1024, m0, n0, ldsA, ldsB, acc);
  short* Tp = Tb + (size_t)b * 256 * 512;
#pragma unroll
  for (int m = 0; m < 4; ++m)
#pragma unroll
    for (int n = 0; n < 4; ++n)
#pragma unroll
      for (int i = 0; i < 4; ++i) {
        int r = m0 + wr + m * 16 + cr + i;
        int c = n0 + wc + n * 16 + cc;
        Tp[(size_t)r * 512 + c] = f2bf(acc[m][n][i]);
      }
}

// A = S1 * Qtb^T; writes out segments 0 (C), 1 (A), 2 (C*A). M=1024,N=512,K=256
__global__ __launch_bounds__(256) void gemm_A(const short* __restrict__ S1,
                                              const short* __restrict__ Qtb,
                                              const float* __restrict__ C,
                                              float* __restrict__ out) {
  GEMM_PROLOGUE();
  gemm_core(S1 + (size_t)b * 1024 * 256, Qtb + (size_t)b * 512 * 256, 256, 256,
            256, m0, n0, ldsA, ldsB, acc);
#pragma unroll
  for (int m = 0; m < 4; ++m)
#pragma unroll
    for (int n = 0; n < 4; ++n)
#pragma unroll
      for (int i = 0; i < 4; ++i) {
        int r = m0 + wr + m * 16 + cr + i;
        int c = n0 + wc + n * 16 + cc;
        float a = acc[m][n][i];
        float cv = C[((size_t)b * 1024 + r) * 512 + c];
        size_t base = ((size_t)b * 1024 + r) * 2048;
        out[base + c] = cv;
        out[base + 512 + c] = a;
        out[base + 1024 + c] = cv * a;
      }
}

// Bt = S1 * Ttb^T; writes out segment 3 (C*Bt). M=1024,N=512,K=256
__global__ __launch_bounds__(256) void gemm_Bt(const short* __restrict__ S1,
                                               const short* __restrict__ Ttb,
                                               const float* __restrict__ C,
                                               float* __restrict__ out) {
  GEMM_PROLOGUE();
  gemm_core(S1 + (size_t)b * 1024 * 256, Ttb + (size_t)b * 512 * 256, 256, 256,
            256, m0, n0, ldsA, ldsB, acc);
#pragma unroll
  for (int m = 0; m < 4; ++m)
#pragma unroll
    for (int n = 0; n < 4; ++n)
#pragma unroll
      for (int i = 0; i < 4; ++i) {
        int r = m0 + wr + m * 16 + cr + i;
        int c = n0 + wc + n * 16 + cc;
        float cv = C[((size_t)b * 1024 + r) * 512 + c];
        size_t base = ((size_t)b * 1024 + r) * 2048;
        out[base + 1536 + c] = cv * acc[m][n][i];
      }
}

// ---------------- masked softmaxes (fp32, exact reference semantics) -------

// rows of S (len 256, mask Qmask[b,lq]); one wave per row; out bf16 S1
__global__ __launch_bounds__(256) void softmax_q(const float* __restrict__ S,
                                                 const int* __restrict__ Qmask,
                                                 short* __restrict__ S1) {
  int wave = threadIdx.x >> 6, lane = threadIdx.x & 63;
  int row = blockIdx.x * 4 + wave;  // b*1024 + lc
  int b = row >> 10;
  const float* s = S + (size_t)row * 256 + lane * 4;
  const int* qm = Qmask + b * 256 + lane * 4;
  float4 x = *(const float4*)s;
  int4 m = *(const int4*)qm;
  float mf[4] = {(float)m.x, (float)m.y, (float)m.z, (float)m.w};
  float xm[4] = {x.x * mf[0], x.y * mf[1], x.z * mf[2], x.w * mf[3]};
  float mx = fmaxf(fmaxf(xm[0], xm[1]), fmaxf(xm[2], xm[3]));
  mx = wave_max(mx);
  float e[4];
  float sum = 0.f;
#pragma unroll
  for (int j = 0; j < 4; ++j) {
    e[j] = mf[j] * expf(xm[j] - mx);
    sum += e[j];
  }
  sum = wave_sum(sum);
  float inv = 1.0f / (sum + 1e-6f);
  short4v o;
#pragma unroll
  for (int j = 0; j < 4; ++j) o[j] = f2bf(e[j] * inv);
  *(short4v*)(S1 + (size_t)row * 256 + lane * 4) = o;
}

// rows of St (len 1024, mask Cmask[b,lc]); one wave per row; out bf16 S2t
__global__ __launch_bounds__(256) void softmax_c(const float* __restrict__ St,
                                                 const int* __restrict__ Cmask,
                                                 short* __restrict__ S2t) {
  int wave = threadIdx.x >> 6, lane = threadIdx.x & 63;
  int row = blockIdx.x * 4 + wave;  // b*256 + lq
  int b = row >> 8;
  const float* s = St + (size_t)row * 1024;
  const int* cm = Cmask + b * 1024;
  float xm[16], mf[16];
  float mx = -1e30f;
#pragma unroll
  for (int ch = 0; ch < 4; ++ch) {
    int idx = ch * 256 + lane * 4;
    float4 x = *(const float4*)(s + idx);
    int4 m = *(const int4*)(cm + idx);
    mf[ch * 4 + 0] = (float)m.x; mf[ch * 4 + 1] = (float)m.y;
    mf[ch * 4 + 2] = (float)m.z; mf[ch * 4 + 3] = (float)m.w;
    xm[ch * 4 + 0] = x.x * mf[ch * 4 + 0];
    xm[ch * 4 + 1] = x.y * mf[ch * 4 + 1];
    xm[ch * 4 + 2] = x.z * mf[ch * 4 + 2];
    xm[ch * 4 + 3] = x.w * mf[ch * 4 + 3];
#pragma unroll
    for (int j = 0; j < 4; ++j) mx = fmaxf(mx, xm[ch * 4 + j]);
  }
  mx = wave_max(mx);
  float e[16];
  float sum = 0.f;
#pragma unroll
  for (int k = 0; k < 16; ++k) {
    e[k] = mf[k] * expf(xm[k] - mx);
    sum += e[k];
  }
  sum = wave_sum(sum);
  float inv = 1.0f / (sum + 1e-6f);
#pragma unroll
  for (int ch = 0; ch < 4; ++ch) {
    short4v o;
#pragma unroll
    for (int j = 0; j < 4; ++j) o[j] = f2bf(e[ch * 4 + j] * inv);
    *(short4v*)(S2t + (size_t)row * 1024 + ch * 256 + lane * 4) = o;
  }
}

// ---------------------------------------------------------------------------

extern "C" void kernel_launch(void* const* d_in, const int* in_sizes, int n_in,
                              void* d_out, int out_size, void* d_ws,
                              size_t ws_size, hipStream_t stream) {
  const float* C = (const float*)d_in[0];
  const float* Q = (const float*)d_in[1];
  const int* Cmask = (const int*)d_in[2];
  const int* Qmask = (const int*)d_in[3];
  const float* w4C = (const float*)d_in[4];
  const float* w4Q = (const float*)d_in[5];
  const float* w4mlu = (const float*)d_in[6];
  const float* bias = (const float*)d_in[7];
  float* out = (float*)d_out;

  size_t off = 0;
  auto alloc = [&](size_t n) {
    void* p = (char*)d_ws + off;
    off += (n + 255) & ~(size_t)255;
    return p;
  };
  float* sub0 = (float*)alloc(16384 * sizeof(float));
  float* sub1 = (float*)alloc(4096 * sizeof(float));
  short* CW = (short*)alloc((size_t)16 * 1024 * 512 * 2);
  short* Qb = (short*)alloc((size_t)16 * 256 * 512 * 2);
  short* Ctb = (short*)alloc((size_t)16 * 512 * 1024 * 2);
  short* Qtb = (short*)alloc((size_t)16 * 512 * 256 * 2);
  float* S = (float*)alloc((size_t)16 * 1024 * 256 * 4);
  float* St = (float*)alloc((size_t)16 * 1024 * 256 * 4);
  short* S1 = (short*)alloc((size_t)16 * 1024 * 256 * 2);
  short* S2t = (short*)alloc((size_t)16 * 1024 * 256 * 2);
  short* Tb = (short*)alloc((size_t)16 * 256 * 512 * 2);
  short* Ttb = (short*)alloc((size_t)16 * 256 * 512 * 2);

  prep_c<<<dim3(4096), dim3(256), 0, stream>>>(C, w4C, w4mlu, sub0, CW);
  prep_q<<<dim3(1024), dim3(256), 0, stream>>>(Q, w4Q, sub1, Qb);
  transpose_k<float, short><<<dim3(16, 32, 16), dim3(256), 0, stream>>>(C, Ctb, 1024, 512);
  transpose_k<float, short><<<dim3(16, 8, 16), dim3(256), 0, stream>>>(Q, Qtb, 256, 512);
  gemm_S<<<dim3(8, 2, 16), dim3(256), 0, stream>>>(CW, Qb, sub0, sub1, bias, S);
  softmax_q<<<dim3(4096), dim3(256), 0, stream>>>(S, Qmask, S1);
  transpose_k<float, float><<<dim3(8, 32, 16), dim3(256), 0, stream>>>(S, St, 1024, 256);
  softmax_c<<<dim3(1024), dim3(256), 0, stream>>>(St, Cmask, S2t);
  gemm_T<<<dim3(2, 4, 16), dim3(256), 0, stream>>>(S2t, Ctb, Tb);
  transpose_k<short, short><<<dim3(16, 8, 16), dim3(256), 0, stream>>>(Tb, Ttb, 256, 512);
  gemm_A<<<dim3(8, 4, 16), dim3(256), 0, stream>>>(S1, Qtb, C, out);
  gemm_Bt<<<dim3(8, 4, 16), dim3(256), 0, stream>>>(S1, Ttb, C, out);
}